// Round 3
// baseline (13997.519 us; speedup 1.0000x reference)
//
#include <hip/hip_runtime.h>
#include <cstdint>

// CharRNN fused kernel, round 3 — MI355X (gfx950).
//
// Topology: 8 clusters x 16 members = 128 wgs (all co-resident on 256 CUs).
// Cluster c owns batch rows [16c,16c+16). Member m owns hidden outputs
// [32m,32m+32) (W_hh bf16 hi+lo fragments register-resident) and vocab rows
// [8m,8m+8) of W_fc (register-resident, k split across waves 2/3).
//
// Numerics: IDENTICAL to round 2 (passed, absmax 7.8e-3): W_hh hi+lo bf16
// 3-term MFMA; h exchanged as 21-bit fixed point + 11-bit gen tag per u32.
//
// Round-3 changes (r2 was poll-storm throughput-bound: 86% idle, full-buffer
// atomic re-sweeps by every thread):
//  - wave 0 polls 32 SENTINEL words only (last-stored word per writer wave);
//    data read ONCE per step (optimistic pre-issue into regs), verified by
//    embedded tags, per-word retry as correctness backstop.
//  - sweep layout: consecutive lanes -> consecutive words (full 128B lines).
//  - h-fragments stored in MFMA frag-order (lane-contiguous 16B) -> stride-1
//    ds_read_b128, kills the 8-way bank conflicts (3.8e8 -> expect <5e7).
//  - BB=16: full A-tile (r2 duplicated half the MFMA rows), half the wgs.
//  - logits fully on waves 2/3 (off critical path), 1-iter software pipeline
//    for the cross-wave k-reduction.

typedef short bf16x8 __attribute__((ext_vector_type(8)));
typedef float f32x4 __attribute__((ext_vector_type(4)));

#define VOCAB 128
#define EMB   16
#define HID   512
#define TT    1024
#define NCL   8      // clusters
#define CLW   16     // members per cluster
#define BB    16     // batch rows per cluster
#define JC    32     // hidden outputs per member
#define NWG   128
#define BUFW  (NCL * BB * HID)   // 65536 words per generation buffer
#define PJC   33                 // padded ep stride

__device__ __forceinline__ unsigned short f2bf(float f) {
  uint32_t u = __builtin_bit_cast(uint32_t, f);
  u += 0x7FFFu + ((u >> 16) & 1u);
  return (unsigned short)(u >> 16);
}
__device__ __forceinline__ float bf2f(unsigned short s) {
  uint32_t u = (uint32_t)s << 16;
  return __builtin_bit_cast(float, u);
}
__device__ __forceinline__ float ftanh(float z) {
  z = fminf(15.f, fmaxf(-15.f, z));
  float e = __expf(2.f * z);
  return (e - 1.f) * __builtin_amdgcn_rcpf(e + 1.f);
}
__device__ __forceinline__ uint32_t aload(const uint32_t* p) {
  return __hip_atomic_load(p, __ATOMIC_RELAXED, __HIP_MEMORY_SCOPE_AGENT);
}
__device__ __forceinline__ void astore(uint32_t* p, uint32_t v) {
  __hip_atomic_store(p, v, __ATOMIC_RELAXED, __HIP_MEMORY_SCOPE_AGENT);
}

__global__ __launch_bounds__(256, 1) void charrnn_kernel(
    const int* __restrict__ xin,
    const float* __restrict__ emb,
    const float* __restrict__ wih,
    const float* __restrict__ whh,
    const float* __restrict__ bih,
    const float* __restrict__ bhh,
    const float* __restrict__ wfc,
    const float* __restrict__ bfc,
    float* __restrict__ out,
    uint32_t* __restrict__ hx)
{
  // frag-order h state: idx = ks*512 + lane*8 + j  (lane = quad_k*16 + row)
  __shared__ __align__(16) unsigned short a_hi[16 * 512];   // 16 KB
  __shared__ __align__(16) unsigned short a_lo[16 * 512];   // 16 KB
  __shared__ float ep[VOCAB * PJC];                         // 16.9 KB
  __shared__ unsigned char xtok[BB * TT];                   // 16 KB
  __shared__ __align__(16) float red[2][256];               // 2 KB logits partials

  const int tid  = threadIdx.x;
  const int wave = tid >> 6;
  const int lane = tid & 63;
  const int col  = lane & 15;
  const int quad = lane >> 4;
  const int cl   = blockIdx.x & 7;   // members of a cluster share blockIdx mod 8
  const int m    = blockIdx.x >> 3;  // -> same XCD under round-robin (perf hint)

  // ---- weight fragments -> registers (global gather, one-time) ----
  bf16x8 wfh[16], wfl[16], wfcf[8];
  if (wave < 2) {
    const int nrow = m * JC + wave * 16 + col;
    const float* wr = whh + (size_t)nrow * HID + quad * 8;
    #pragma unroll
    for (int ks = 0; ks < 16; ++ks) {
      bf16x8 hi, lo;
      #pragma unroll
      for (int j = 0; j < 8; ++j) {
        float w = wr[ks * 32 + j];
        unsigned short h = f2bf(w);
        hi[j] = (short)h;
        lo[j] = (short)f2bf(w - bf2f(h));
      }
      wfh[ks] = hi; wfl[ks] = lo;
    }
  } else {
    const int vrow = m * 8 + (col & 7);
    const float* wr = wfc + (size_t)vrow * HID + (wave - 2) * 256 + quad * 8;
    #pragma unroll
    for (int ks = 0; ks < 8; ++ks) {
      bf16x8 f;
      #pragma unroll
      for (int j = 0; j < 8; ++j) f[j] = (short)f2bf(wr[ks * 32 + j]);
      wfcf[ks] = f;
    }
  }
  const float bfcr = bfc[m * 8 + (col & 7)];

  // ---- LDS init: h0 = 0, ep table, tokens ----
  for (int i = tid; i < 16 * 512; i += 256) { a_hi[i] = 0; a_lo[i] = 0; }
  for (int i = tid; i < VOCAB * JC; i += 256) {
    int v = i >> 5, jl = i & 31;
    int jg = m * JC + jl;
    float s = bih[jg] + bhh[jg];
    #pragma unroll
    for (int e = 0; e < EMB; ++e) s += emb[v * EMB + e] * wih[jg * EMB + e];
    ep[v * PJC + jl] = s;
  }
  for (int i = tid; i < BB * TT; i += 256) {
    int b = i >> 10, t = i & 1023;
    xtok[i] = (unsigned char)xin[(cl * BB + b) * TT + t];
  }
  __syncthreads();

  // ---- main time loop ----
  const int lw = tid & 31;       // word-in-32-chunk (consecutive lanes -> words)
  const int r0 = tid >> 5;       // handles rows r0 and r0+8
  const float rcp20 = 1.f / 1048576.f;
  f32x4 prev_lacc = {0.f, 0.f, 0.f, 0.f};

  #pragma unroll 1
  for (int t = 0; t <= TT + 1; ++t) {
    const int par = t & 1;
    const uint32_t tag = (uint32_t)t & 0x7FFu;
    uint32_t* const p0 = hx + par * BUFW + (cl * BB + r0) * HID + lw;
    uint32_t* const p1 = p0 + 8 * HID;
    uint32_t v0[16], v1[16];

    // -- phase A: logits partials to LDS; optimistic data sweep; sentinel poll --
    if (wave >= 2 && t >= 2) {
      *(f32x4*)&red[wave - 2][lane * 4] = prev_lacc;
    }
    if (t >= 1 && t <= TT) {
      #pragma unroll
      for (int i = 0; i < 16; ++i) {
        v0[i] = aload(p0 + 32 * i);
        v1[i] = aload(p1 + 32 * i);
      }
      if (wave == 0) {
        // sentinels: word (cl*16+15)*512 + w*16, w=0..31 (one per writer wave)
        const uint32_t* sp = hx + par * BUFW + (cl * BB + 15) * HID + (lane & 31) * 16;
        for (;;) {
          uint32_t sv = aload(sp);
          bool ok = (lane >= 32) || ((sv & 0x7FFu) == tag);
          if (__ballot(ok) == ~0ull) break;
        }
      }
    }
    __syncthreads();  // B1: sentinels seen; red stored

    // -- phase B: verify + convert to frag-order hi/lo LDS; retry stragglers --
    if (t >= 1 && t <= TT) {
      const int qk = lw >> 3, jj = lw & 7;
      const int idx0 = ((qk << 4) + r0) * 8 + jj;        // + ks*512
      const int idx1 = ((qk << 4) + r0 + 8) * 8 + jj;
      uint32_t pend = 0;
      #pragma unroll
      for (int i = 0; i < 16; ++i) {
        if ((v0[i] & 0x7FFu) == tag) {
          float h = (float)(((int)v0[i]) >> 11) * rcp20;
          uint32_t uh = __builtin_bit_cast(uint32_t, h) & 0xFFFF0000u;
          float l = h - __builtin_bit_cast(float, uh);
          a_hi[i * 512 + idx0] = (unsigned short)(uh >> 16);
          a_lo[i * 512 + idx0] = (unsigned short)(__builtin_bit_cast(uint32_t, l) >> 16);
        } else pend |= 1u << i;
        if ((v1[i] & 0x7FFu) == tag) {
          float h = (float)(((int)v1[i]) >> 11) * rcp20;
          uint32_t uh = __builtin_bit_cast(uint32_t, h) & 0xFFFF0000u;
          float l = h - __builtin_bit_cast(float, uh);
          a_hi[i * 512 + idx1] = (unsigned short)(uh >> 16);
          a_lo[i * 512 + idx1] = (unsigned short)(__builtin_bit_cast(uint32_t, l) >> 16);
        } else pend |= 1u << (16 + i);
      }
      while (pend) {
        uint32_t np = 0;
        #pragma unroll
        for (int i = 0; i < 16; ++i) {
          if (pend & (1u << i)) {
            uint32_t v = aload(p0 + 32 * i);
            if ((v & 0x7FFu) == tag) {
              float h = (float)(((int)v) >> 11) * rcp20;
              uint32_t uh = __builtin_bit_cast(uint32_t, h) & 0xFFFF0000u;
              float l = h - __builtin_bit_cast(float, uh);
              a_hi[i * 512 + idx0] = (unsigned short)(uh >> 16);
              a_lo[i * 512 + idx0] = (unsigned short)(__builtin_bit_cast(uint32_t, l) >> 16);
            } else np |= 1u << i;
          }
          if (pend & (1u << (16 + i))) {
            uint32_t v = aload(p1 + 32 * i);
            if ((v & 0x7FFu) == tag) {
              float h = (float)(((int)v) >> 11) * rcp20;
              uint32_t uh = __builtin_bit_cast(uint32_t, h) & 0xFFFF0000u;
              float l = h - __builtin_bit_cast(float, uh);
              a_hi[i * 512 + idx1] = (unsigned short)(uh >> 16);
              a_lo[i * 512 + idx1] = (unsigned short)(__builtin_bit_cast(uint32_t, l) >> 16);
            } else np |= 1u << (16 + i);
          }
        }
        pend = np;
      }
    }
    __syncthreads();  // B2: lds_a(gen t) ready

    // -- phase C --
    if (wave < 2) {
      // recurrence: gen t -> gen t+1 (3-term hi/lo MFMA), publish
      if (t < TT) {
        f32x4 acc0 = {0.f,0.f,0.f,0.f}, acc1 = {0.f,0.f,0.f,0.f}, acc2 = {0.f,0.f,0.f,0.f};
        #pragma unroll
        for (int ks = 0; ks < 16; ++ks) {
          bf16x8 ah = *(const bf16x8*)&a_hi[ks * 512 + lane * 8];
          bf16x8 al = *(const bf16x8*)&a_lo[ks * 512 + lane * 8];
          acc0 = __builtin_amdgcn_mfma_f32_16x16x32_bf16(ah, wfh[ks], acc0, 0, 0, 0);
          acc1 = __builtin_amdgcn_mfma_f32_16x16x32_bf16(al, wfh[ks], acc1, 0, 0, 0);
          acc2 = __builtin_amdgcn_mfma_f32_16x16x32_bf16(ah, wfl[ks], acc2, 0, 0, 0);
        }
        const int jl = wave * 16 + col;
        const uint32_t ntag = (uint32_t)(t + 1) & 0x7FFu;
        uint32_t* wb = hx + ((t + 1) & 1) * BUFW + (cl * BB) * HID + m * JC + jl;
        #pragma unroll
        for (int i = 0; i < 4; ++i) {
          const int b = quad * 4 + i;   // b=15 (sentinel) stored last by quad 3
          float z = acc0[i] + acc1[i] + acc2[i]
                  + ep[(int)xtok[b * TT + t] * PJC + jl];
          float h = ftanh(z);
          int q = __float2int_rn(h * 1048576.f);
          q = max(min(q, 1048575), -1048576);
          astore(wb + b * HID, ((uint32_t)q << 11) | ntag);
        }
      }
    } else {
      // reduce + store logits for time t-2 (wave 2; partials in red from A)
      if (wave == 2 && t >= 2 && col < 8) {
        #pragma unroll
        for (int i = 0; i < 4; ++i) {
          const int b = quad * 4 + i;
          float s = red[0][lane * 4 + i] + red[1][lane * 4 + i] + bfcr;
          out[((size_t)(cl * BB + b) * TT + (t - 2)) * VOCAB + m * 8 + col] = s;
        }
      }
      // logits MFMA for time t-1 (k-half per wave, hi+lo terms)
      if (t >= 1 && t <= TT) {
        f32x4 lacc = {0.f, 0.f, 0.f, 0.f};
        const int kb = (wave - 2) * 8;
        #pragma unroll
        for (int ks = 0; ks < 8; ++ks) {
          bf16x8 ah = *(const bf16x8*)&a_hi[(kb + ks) * 512 + lane * 8];
          bf16x8 al = *(const bf16x8*)&a_lo[(kb + ks) * 512 + lane * 8];
          lacc = __builtin_amdgcn_mfma_f32_16x16x32_bf16(ah, wfcf[ks], lacc, 0, 0, 0);
          lacc = __builtin_amdgcn_mfma_f32_16x16x32_bf16(al, wfcf[ks], lacc, 0, 0, 0);
        }
        prev_lacc = lacc;
      }
    }
  }
}

extern "C" void kernel_launch(void* const* d_in, const int* in_sizes, int n_in,
                              void* d_out, int out_size, void* d_ws, size_t ws_size,
                              hipStream_t stream) {
  (void)in_sizes; (void)n_in; (void)out_size;
  if (ws_size < (size_t)2 * BUFW * sizeof(uint32_t)) return;  // 512 KB scratch

  const int*   x    = (const int*)d_in[0];
  const float* embp = (const float*)d_in[1];
  const float* W_ih = (const float*)d_in[2];
  const float* W_hh = (const float*)d_in[3];
  const float* b_ih = (const float*)d_in[4];
  const float* b_hh = (const float*)d_in[5];
  const float* W_fc = (const float*)d_in[6];
  const float* b_fc = (const float*)d_in[7];

  charrnn_kernel<<<NWG, 256, 0, stream>>>(x, embp, W_ih, W_hh, b_ih, b_hh, W_fc, b_fc,
                                          (float*)d_out, (uint32_t*)d_ws);
}

// Round 4
// 3287.700 us; speedup vs baseline: 4.2575x; 4.2575x over previous
//
#include <hip/hip_runtime.h>
#include <cstdint>

// CharRNN fused kernel, round 4 — MI355X (gfx950).
//
// Topology: 8 clusters x 16 members = 128 wgs. Cluster c owns batch rows
// [16c,16c+16). Member m owns hidden outputs [32m,32m+32) (W_hh bf16 hi+lo
// register-resident) and vocab rows [8m,8m+8) of W_fc (k split, waves 2/3).
//
// Numerics: IDENTICAL to r2/r3 (passed, absmax 7.8e-3): W_hh hi+lo bf16
// 3-term MFMA; h as 21-bit fixed point + 11-bit gen tag per u32; fp32 acc.
//
// Round-4 exchange protocol (r3's optimistic-read + branchy per-word retry
// serialized ~32 x ~1000cy latencies per step = 33k cy/step; r2's continuous
// full-buffer poll storm congested the fabric = 11k cy/step):
//  - one monotonic u32 counter per cluster (own 128B line, zeroed by a
//    hipMemsetAsync before launch). Writer waves atomicAdd(+1) after issuing
//    their data stores -> gen t complete when cnt >= 32*t.
//  - readers spin on that single shared word (coalesced: whole cluster polls
//    one line), THEN issue the 32-word data sweep as straight-line batched
//    loads; embedded tags re-verified; rare stragglers retry the WHOLE
//    batched sweep (one latency per round, never per-word serial chains).

typedef short bf16x8 __attribute__((ext_vector_type(8)));
typedef float f32x4 __attribute__((ext_vector_type(4)));

#define VOCAB 128
#define EMB   16
#define HID   512
#define TT    1024
#define NCL   8      // clusters
#define BB    16     // batch rows per cluster
#define JC    32     // hidden outputs per member
#define NWG   128
#define BUFW  (NCL * BB * HID)   // 65536 words per generation buffer
#define CNTOFF (2 * BUFW)        // u32 index of counter region (8 x 32 u32)
#define PJC   33                 // padded ep stride

__device__ __forceinline__ unsigned short f2bf(float f) {
  uint32_t u = __builtin_bit_cast(uint32_t, f);
  u += 0x7FFFu + ((u >> 16) & 1u);
  return (unsigned short)(u >> 16);
}
__device__ __forceinline__ float bf2f(unsigned short s) {
  uint32_t u = (uint32_t)s << 16;
  return __builtin_bit_cast(float, u);
}
__device__ __forceinline__ float ftanh(float z) {
  z = fminf(15.f, fmaxf(-15.f, z));
  float e = __expf(2.f * z);
  return (e - 1.f) * __builtin_amdgcn_rcpf(e + 1.f);
}
__device__ __forceinline__ uint32_t aload(const uint32_t* p) {
  return __hip_atomic_load(p, __ATOMIC_RELAXED, __HIP_MEMORY_SCOPE_AGENT);
}
__device__ __forceinline__ void astore(uint32_t* p, uint32_t v) {
  __hip_atomic_store(p, v, __ATOMIC_RELAXED, __HIP_MEMORY_SCOPE_AGENT);
}

__global__ __launch_bounds__(256, 1) void charrnn_kernel(
    const int* __restrict__ xin,
    const float* __restrict__ emb,
    const float* __restrict__ wih,
    const float* __restrict__ whh,
    const float* __restrict__ bih,
    const float* __restrict__ bhh,
    const float* __restrict__ wfc,
    const float* __restrict__ bfc,
    float* __restrict__ out,
    uint32_t* __restrict__ hx)
{
  // frag-order h state: idx = ks*512 + lane*8 + j  (lane = quad_k*16 + row)
  __shared__ __align__(16) unsigned short a_hi[16 * 512];   // 16 KB
  __shared__ __align__(16) unsigned short a_lo[16 * 512];   // 16 KB
  __shared__ float ep[VOCAB * PJC];                         // 16.9 KB
  __shared__ unsigned char xtok[BB * TT];                   // 16 KB
  __shared__ __align__(16) float red[2][256];               // 2 KB logits partials

  const int tid  = threadIdx.x;
  const int wave = tid >> 6;
  const int lane = tid & 63;
  const int col  = lane & 15;
  const int quad = lane >> 4;
  const int cl   = blockIdx.x & 7;   // members of a cluster share blockIdx mod 8
  const int m    = blockIdx.x >> 3;  // -> same XCD under round-robin (perf hint)

  // ---- weight fragments -> registers (global gather, one-time) ----
  bf16x8 wfh[16], wfl[16], wfcf[8];
  if (wave < 2) {
    const int nrow = m * JC + wave * 16 + col;
    const float* wr = whh + (size_t)nrow * HID + quad * 8;
    #pragma unroll
    for (int ks = 0; ks < 16; ++ks) {
      bf16x8 hi, lo;
      #pragma unroll
      for (int j = 0; j < 8; ++j) {
        float w = wr[ks * 32 + j];
        unsigned short h = f2bf(w);
        hi[j] = (short)h;
        lo[j] = (short)f2bf(w - bf2f(h));
      }
      wfh[ks] = hi; wfl[ks] = lo;
    }
  } else {
    const int vrow = m * 8 + (col & 7);
    const float* wr = wfc + (size_t)vrow * HID + (wave - 2) * 256 + quad * 8;
    #pragma unroll
    for (int ks = 0; ks < 8; ++ks) {
      bf16x8 f;
      #pragma unroll
      for (int j = 0; j < 8; ++j) f[j] = (short)f2bf(wr[ks * 32 + j]);
      wfcf[ks] = f;
    }
  }
  const float bfcr = bfc[m * 8 + (col & 7)];

  // ---- LDS init: h0 = 0, ep table, tokens ----
  for (int i = tid; i < 16 * 512; i += 256) { a_hi[i] = 0; a_lo[i] = 0; }
  for (int i = tid; i < VOCAB * JC; i += 256) {
    int v = i >> 5, jl = i & 31;
    int jg = m * JC + jl;
    float s = bih[jg] + bhh[jg];
    #pragma unroll
    for (int e = 0; e < EMB; ++e) s += emb[v * EMB + e] * wih[jg * EMB + e];
    ep[v * PJC + jl] = s;
  }
  for (int i = tid; i < BB * TT; i += 256) {
    int b = i >> 10, t = i & 1023;
    xtok[i] = (unsigned char)xin[(cl * BB + b) * TT + t];
  }
  __syncthreads();

  // ---- main time loop ----
  const int lw = tid & 31;       // word-in-32-chunk (consecutive lanes -> words)
  const int r0 = tid >> 5;       // handles rows r0 and r0+8
  const float rcp20 = 1.f / 1048576.f;
  uint32_t* const cnt = hx + CNTOFF + cl * 32;   // one line per cluster
  f32x4 prev_lacc = {0.f, 0.f, 0.f, 0.f};

  #pragma unroll 1
  for (int t = 0; t <= TT + 1; ++t) {
    const int par = t & 1;
    const uint32_t tag = (uint32_t)t & 0x7FFu;
    uint32_t* const p0 = hx + par * BUFW + (cl * BB + r0) * HID + lw;
    uint32_t* const p1 = p0 + 8 * HID;

    // -- phase A: logits partials (computed in prior C) to LDS --
    if (wave >= 2 && t >= 2) {
      *(f32x4*)&red[wave - 2][lane * 4] = prev_lacc;
    }

    // -- phase B: counter gate, then batched sweep + convert to frag-order --
    if (t >= 1 && t <= TT) {
      const uint32_t target = 32u * (uint32_t)t;
      while ((int32_t)(aload(cnt) - target) < 0) {}   // cheap shared-line spin

      const int qk = lw >> 3, jj = lw & 7;
      const int idx0 = ((qk << 4) + r0) * 8 + jj;     // + ks*512
      const int idx1 = idx0 + 64;                     // row r0+8
      for (;;) {
        uint32_t v0[16], v1[16];
        #pragma unroll
        for (int i = 0; i < 16; ++i) v0[i] = aload(p0 + 32 * i);
        #pragma unroll
        for (int i = 0; i < 16; ++i) v1[i] = aload(p1 + 32 * i);
        uint32_t bad = 0;
        #pragma unroll
        for (int i = 0; i < 16; ++i) bad |= (v0[i] ^ tag) | (v1[i] ^ tag);
        if ((bad & 0x7FFu) == 0) {
          #pragma unroll
          for (int i = 0; i < 16; ++i) {
            float h0 = (float)(((int)v0[i]) >> 11) * rcp20;
            uint32_t uh0 = __builtin_bit_cast(uint32_t, h0) & 0xFFFF0000u;
            float l0 = h0 - __builtin_bit_cast(float, uh0);
            a_hi[i * 512 + idx0] = (unsigned short)(uh0 >> 16);
            a_lo[i * 512 + idx0] = (unsigned short)(__builtin_bit_cast(uint32_t, l0) >> 16);
            float h1 = (float)(((int)v1[i]) >> 11) * rcp20;
            uint32_t uh1 = __builtin_bit_cast(uint32_t, h1) & 0xFFFF0000u;
            float l1 = h1 - __builtin_bit_cast(float, uh1);
            a_hi[i * 512 + idx1] = (unsigned short)(uh1 >> 16);
            a_lo[i * 512 + idx1] = (unsigned short)(__builtin_bit_cast(uint32_t, l1) >> 16);
          }
          break;
        }
      }
    }
    __syncthreads();  // B1: lds_a(gen t) ready; red stored

    // -- phase C --
    if (wave < 2) {
      // recurrence: gen t -> gen t+1 (3-term hi/lo MFMA), publish + count
      if (t < TT) {
        f32x4 acc0 = {0.f,0.f,0.f,0.f}, acc1 = {0.f,0.f,0.f,0.f}, acc2 = {0.f,0.f,0.f,0.f};
        #pragma unroll
        for (int ks = 0; ks < 16; ++ks) {
          bf16x8 ah = *(const bf16x8*)&a_hi[ks * 512 + lane * 8];
          bf16x8 al = *(const bf16x8*)&a_lo[ks * 512 + lane * 8];
          acc0 = __builtin_amdgcn_mfma_f32_16x16x32_bf16(ah, wfh[ks], acc0, 0, 0, 0);
          acc1 = __builtin_amdgcn_mfma_f32_16x16x32_bf16(al, wfh[ks], acc1, 0, 0, 0);
          acc2 = __builtin_amdgcn_mfma_f32_16x16x32_bf16(ah, wfl[ks], acc2, 0, 0, 0);
        }
        const int jl = wave * 16 + col;
        const uint32_t ntag = (uint32_t)(t + 1) & 0x7FFu;
        uint32_t* wb = hx + ((t + 1) & 1) * BUFW + (cl * BB) * HID + m * JC + jl;
        #pragma unroll
        for (int i = 0; i < 4; ++i) {
          const int b = quad * 4 + i;
          float z = acc0[i] + acc1[i] + acc2[i]
                  + ep[(int)xtok[b * TT + t] * PJC + jl];
          float h = ftanh(z);
          int q = __float2int_rn(h * 1048576.f);
          q = max(min(q, 1048575), -1048576);
          astore(wb + b * HID, ((uint32_t)q << 11) | ntag);
        }
        if (lane == 0)
          (void)__hip_atomic_fetch_add(cnt, 1u, __ATOMIC_RELAXED,
                                       __HIP_MEMORY_SCOPE_AGENT);
      }
    } else {
      // reduce + store logits for time t-2 (wave 2; partials in red from A)
      if (wave == 2 && t >= 2 && col < 8) {
        #pragma unroll
        for (int i = 0; i < 4; ++i) {
          const int b = quad * 4 + i;
          float s = red[0][lane * 4 + i] + red[1][lane * 4 + i] + bfcr;
          out[((size_t)(cl * BB + b) * TT + (t - 2)) * VOCAB + m * 8 + col] = s;
        }
      }
      // logits MFMA for time t-1 (k-half per wave, hi+lo terms)
      if (t >= 1 && t <= TT) {
        f32x4 lacc = {0.f, 0.f, 0.f, 0.f};
        const int kb = (wave - 2) * 8;
        #pragma unroll
        for (int ks = 0; ks < 8; ++ks) {
          bf16x8 ah = *(const bf16x8*)&a_hi[(kb + ks) * 512 + lane * 8];
          bf16x8 al = *(const bf16x8*)&a_lo[(kb + ks) * 512 + lane * 8];
          lacc = __builtin_amdgcn_mfma_f32_16x16x32_bf16(ah, wfcf[ks], lacc, 0, 0, 0);
          lacc = __builtin_amdgcn_mfma_f32_16x16x32_bf16(al, wfcf[ks], lacc, 0, 0, 0);
        }
        prev_lacc = lacc;
      }
    }
    __syncthreads();  // B2: lds_a consumed; red consumed
  }
}

extern "C" void kernel_launch(void* const* d_in, const int* in_sizes, int n_in,
                              void* d_out, int out_size, void* d_ws, size_t ws_size,
                              hipStream_t stream) {
  (void)in_sizes; (void)n_in; (void)out_size;
  if (ws_size < (size_t)CNTOFF * sizeof(uint32_t) + 4096) return;  // 512 KB + counters

  const int*   x    = (const int*)d_in[0];
  const float* embp = (const float*)d_in[1];
  const float* W_ih = (const float*)d_in[2];
  const float* W_hh = (const float*)d_in[3];
  const float* b_ih = (const float*)d_in[4];
  const float* b_hh = (const float*)d_in[5];
  const float* W_fc = (const float*)d_in[6];
  const float* b_fc = (const float*)d_in[7];

  // zero the per-cluster counters (8 x 32 u32); data region keeps 0xAA poison
  hipMemsetAsync((uint32_t*)d_ws + CNTOFF, 0, NCL * 32 * sizeof(uint32_t), stream);

  charrnn_kernel<<<NWG, 256, 0, stream>>>(x, embp, W_ih, W_hh, b_ih, b_hh, W_fc, b_fc,
                                          (float*)d_out, (uint32_t*)d_ws);
}